// Round 1
// baseline (223.133 us; speedup 1.0000x reference)
//
#include <hip/hip_runtime.h>

#define IMG 128
#define OUTD 64

__global__ __launch_bounds__(256) void crop_resize_kernel(
    const float* __restrict__ x,      // (4,1,128,128,128) f32
    const int* __restrict__ sizes,    // (4,64) i32
    const int* __restrict__ starts,   // (4,64,3) i32
    float* __restrict__ out)          // (256,64,64,64) f32
{
    int idx = blockIdx.x * 256 + threadIdx.x;   // total = 256<<18 = 67,108,864
    int w_o = idx & 63;
    int h_o = (idx >> 6) & 63;
    int d_o = (idx >> 12) & 63;
    int crop = idx >> 18;                        // 0..255
    int b = crop >> 6;                           // 0..3

    int sz  = sizes[crop];
    int s_d = starts[crop * 3 + 0];
    int s_h = starts[crop * 3 + 1];
    int s_w = starts[crop * 3 + 2];

    float szf   = (float)sz;
    float scale = szf * (1.0f / 64.0f);          // sz/64 exact (pow2 divisor)
    float szm1  = szf - 1.0f;
    int   szm1i = sz - 1;

    // axis coords, matching reference f32 math
    auto coords = [&](int j, int start, int& a0, int& a1, float& w) {
        float src = ((float)j + 0.5f) * scale - 0.5f;
        src = fminf(fmaxf(src, 0.0f), szm1);
        float fl = floorf(src);
        int i0 = (int)fl;
        int i1 = min(i0 + 1, szm1i);
        w = src - fl;
        a0 = start + i0;
        a1 = start + i1;
    };

    int d0, d1, h0, h1, w0, w1;
    float wd, wh, ww;
    coords(d_o, s_d, d0, d1, wd);
    coords(h_o, s_h, h0, h1, wh);
    coords(w_o, s_w, w0, w1, ww);

    const float* vol = x + (long long)b * (IMG * IMG * IMG);

    auto g = [&](int a, int bb, int c) -> float {
        return vol[(a * IMG + bb) * IMG + c];
    };

    float c00 = g(d0, h0, w0) * (1.0f - ww) + g(d0, h0, w1) * ww;
    float c01 = g(d0, h1, w0) * (1.0f - ww) + g(d0, h1, w1) * ww;
    float c10 = g(d1, h0, w0) * (1.0f - ww) + g(d1, h0, w1) * ww;
    float c11 = g(d1, h1, w0) * (1.0f - ww) + g(d1, h1, w1) * ww;

    float c0 = c00 * (1.0f - wh) + c01 * wh;
    float c1 = c10 * (1.0f - wh) + c11 * wh;
    out[idx] = c0 * (1.0f - wd) + c1 * wd;
}

extern "C" void kernel_launch(void* const* d_in, const int* in_sizes, int n_in,
                              void* d_out, int out_size, void* d_ws, size_t ws_size,
                              hipStream_t stream) {
    const float* x      = (const float*)d_in[0];
    const int*   sizes  = (const int*)d_in[1];
    const int*   starts = (const int*)d_in[2];
    float*       out    = (float*)d_out;

    int total  = 256 << 18;            // 67,108,864 output elements
    int blocks = total / 256;          // 262,144
    crop_resize_kernel<<<blocks, 256, 0, stream>>>(x, sizes, starts, out);
}

// Round 2
// 166.639 us; speedup vs baseline: 1.3390x; 1.3390x over previous
//
#include <hip/hip_runtime.h>

#define IMG 128
#define PLANE (IMG * IMG)
#define VOLSZ (IMG * IMG * IMG)

// One block per (crop, d_o): 256 threads = 4 waves.
// lane (0..63) = w_out; each wave handles 16 of the 64 h_out rows.
// crop/d_o/h are wave-uniform -> scalar addressing; only w varies per lane.
__global__ __launch_bounds__(256) void crop_resize_kernel(
    const float* __restrict__ x,      // (4,1,128,128,128) f32
    const int* __restrict__ sizes,    // (4,64) i32
    const int* __restrict__ starts,   // (4,64,3) i32
    float* __restrict__ out)          // (256,64,64,64) f32
{
    // XCD-chunked swizzle: 16384 blocks, 8 XCDs, 2048 per chunk (bijective).
    // Chunk k = crops [k*32, k*32+32) -> each source volume served by 2 XCDs.
    int bid  = blockIdx.x;
    int swz  = (bid & 7) * 2048 + (bid >> 3);
    int crop = swz >> 6;              // 0..255
    int d_o  = swz & 63;
    int b    = crop >> 6;

    int sz  = sizes[crop];            // uniform -> scalar loads
    int s_d = starts[crop * 3 + 0];
    int s_h = starts[crop * 3 + 1];
    int s_w = starts[crop * 3 + 2];

    float szf   = (float)sz;
    float scale = szf * (1.0f / 64.0f);   // exact (pow2 divisor)
    float szm1  = szf - 1.0f;
    int   szm1i = sz - 1;

    int lane = threadIdx.x & 63;
    int wid  = __builtin_amdgcn_readfirstlane(threadIdx.x >> 6);

    // (i0, i1, frac) for j = lane — identical for w and h axes (same sz).
    float src = ((float)lane + 0.5f) * scale - 0.5f;
    src = fminf(fmaxf(src, 0.0f), szm1);
    float fl = floorf(src);
    int   i0 = (int)fl;
    int   i1 = min(i0 + 1, szm1i);
    float fr = src - fl;

    // w-axis per-lane element offsets
    int   wo0  = s_w + i0;
    int   wo1  = s_w + i1;
    float ww   = fr;
    float omww = 1.0f - ww;

    // h-axis per-lane row offsets (broadcast later via readlane)
    int ho0 = (s_h + i0) * IMG;
    int ho1 = (s_h + i1) * IMG;

    // d coords for j = d_o (uniform) — recompute once
    float srcd = ((float)d_o + 0.5f) * scale - 0.5f;
    srcd = fminf(fmaxf(srcd, 0.0f), szm1);
    float fld = floorf(srcd);
    int   di0 = (int)fld;
    int   di1 = min(di0 + 1, szm1i);
    float wd  = srcd - fld;

    const float* vol = x + (long long)b * VOLSZ;
    const float* pd0 = vol + (s_d + di0) * PLANE;
    const float* pd1 = vol + (s_d + di1) * PLANE;

    float* orow = out + (((long long)crop * 64 + d_o) * 64) * 64 + lane;

    #pragma unroll 4
    for (int it = 0; it < 16; ++it) {
        int h = wid + it * 4;   // wave-uniform scalar (wid is SGPR)

        int   rh0 = __builtin_amdgcn_readlane(ho0, h);
        int   rh1 = __builtin_amdgcn_readlane(ho1, h);
        float wh  = __int_as_float(__builtin_amdgcn_readlane(__float_as_int(fr), h));

        const float* r00 = pd0 + rh0;
        const float* r01 = pd0 + rh1;
        const float* r10 = pd1 + rh0;
        const float* r11 = pd1 + rh1;

        // w-lerp exactly as reference: a*(1-ww) + b*ww
        float v00 = r00[wo0] * omww + r00[wo1] * ww;
        float v01 = r01[wo0] * omww + r01[wo1] * ww;
        float v10 = r10[wo0] * omww + r10[wo1] * ww;
        float v11 = r11[wo0] * omww + r11[wo1] * ww;

        float c0 = v00 + (v01 - v00) * wh;
        float c1 = v10 + (v11 - v10) * wh;
        orow[h * 64] = c0 + (c1 - c0) * wd;
    }
}

extern "C" void kernel_launch(void* const* d_in, const int* in_sizes, int n_in,
                              void* d_out, int out_size, void* d_ws, size_t ws_size,
                              hipStream_t stream) {
    const float* x      = (const float*)d_in[0];
    const int*   sizes  = (const int*)d_in[1];
    const int*   starts = (const int*)d_in[2];
    float*       out    = (float*)d_out;

    int blocks = 256 * 64;   // (crop, d_o)
    crop_resize_kernel<<<blocks, 256, 0, stream>>>(x, sizes, starts, out);
}

// Round 4
// 153.202 us; speedup vs baseline: 1.4565x; 1.0877x over previous
//
#include <hip/hip_runtime.h>

#define IMG 128
#define PLANE (IMG * IMG)
#define VOLSZ (IMG * IMG * IMG)

// One block per (crop, d_o): 256 threads = 4 waves.
// lane = w_out; each wave handles 16 of the 64 h_out rows.
// Per input row, wave loads the contiguous segment [s_w, s_w+sz] coalesced
// (1-2 wave loads) and extracts per-lane w0/w1 values via shfl.
// NOTE: all __shfl calls are unconditional straight-line code (full exec
// mask); selection between low/high segment halves is a value select.
__global__ __launch_bounds__(256) void crop_resize_kernel(
    const float* __restrict__ x,      // (4,1,128,128,128) f32
    const int* __restrict__ sizes,    // (4,64) i32
    const int* __restrict__ starts,   // (4,64,3) i32
    float* __restrict__ out)          // (256,64,64,64) f32
{
    // XCD-chunked swizzle (16384 blocks, %8==0 -> bijective)
    int bid  = blockIdx.x;
    int swz  = (bid & 7) * 2048 + (bid >> 3);
    int crop = swz >> 6;
    int d_o  = swz & 63;
    int b    = crop >> 6;

    int sz  = sizes[crop];            // wave-uniform -> scalar
    int s_d = starts[crop * 3 + 0];
    int s_h = starts[crop * 3 + 1];
    int s_w = starts[crop * 3 + 2];

    float szf   = (float)sz;
    float scale = szf * (1.0f / 64.0f);
    float szm1  = szf - 1.0f;
    int   szm1i = sz - 1;

    int lane = threadIdx.x & 63;
    int wid  = __builtin_amdgcn_readfirstlane(threadIdx.x >> 6);

    // per-lane (i0, i1, frac) for j = lane — shared by w and h axes
    float srcj = ((float)lane + 0.5f) * scale - 0.5f;
    srcj = fminf(fmaxf(srcj, 0.0f), szm1);
    float flj = floorf(srcj);
    int   i0  = (int)flj;
    int   i1  = min(i0 + 1, szm1i);
    float fr  = srcj - flj;

    // w axis: segment-relative extraction indices + weights
    float ww = fr, omww = 1.0f - fr;
    int  wi0 = i0 & 63;
    int  wi1 = i1 & 63;
    bool hi0 = (i0 >= 64);
    bool hi1 = (i1 >= 64);

    // h axis: per-lane row offsets (broadcast via readlane)
    int ho0 = (s_h + i0) * IMG;
    int ho1 = (s_h + i1) * IMG;

    // d axis (uniform)
    float srcd = ((float)d_o + 0.5f) * scale - 0.5f;
    srcd = fminf(fmaxf(srcd, 0.0f), szm1);
    float fld = floorf(srcd);
    int   di0 = (int)fld;
    int   di1 = min(di0 + 1, szm1i);
    float wd  = srcd - fld;

    const float* vol = x + (long long)b * VOLSZ;
    const float* pd0 = vol + (s_d + di0) * PLANE + s_w;
    const float* pd1 = vol + (s_d + di1) * PLANE + s_w;

    // cooperative segment column offsets (clamped to stay in-row at tail;
    // clamped lanes are never consumed by shfl extraction)
    int colA = min(s_w + lane, IMG - 1) - s_w;        // segment[lane]
    int colB = min(s_w + 64 + lane, IMG - 1) - s_w;   // segment[64+lane]

    float* orow = out + (((long long)crop * 64 + d_o) * 64) * 64 + lane;

    if (sz > 64) {
        #pragma unroll 4
        for (int it = 0; it < 16; ++it) {
            int   h   = wid + it * 4;
            int   rh0 = __builtin_amdgcn_readlane(ho0, h);
            int   rh1 = __builtin_amdgcn_readlane(ho1, h);
            float wh  = __int_as_float(__builtin_amdgcn_readlane(__float_as_int(fr), h));

            const float* rA = pd0 + rh0;
            const float* rB = pd0 + rh1;
            const float* rC = pd1 + rh0;
            const float* rD = pd1 + rh1;

            float aL = rA[colA], aH = rA[colB];
            float bL = rB[colA], bH = rB[colB];
            float cL = rC[colA], cH = rC[colB];
            float dL = rD[colA], dH = rD[colB];

            // unconditional shuffles (full exec), then value-selects
            float a0L = __shfl(aL, wi0, 64), a0H = __shfl(aH, wi0, 64);
            float a1L = __shfl(aL, wi1, 64), a1H = __shfl(aH, wi1, 64);
            float b0L = __shfl(bL, wi0, 64), b0H = __shfl(bH, wi0, 64);
            float b1L = __shfl(bL, wi1, 64), b1H = __shfl(bH, wi1, 64);
            float c0L = __shfl(cL, wi0, 64), c0H = __shfl(cH, wi0, 64);
            float c1L = __shfl(cL, wi1, 64), c1H = __shfl(cH, wi1, 64);
            float d0L = __shfl(dL, wi0, 64), d0H = __shfl(dH, wi0, 64);
            float d1L = __shfl(dL, wi1, 64), d1H = __shfl(dH, wi1, 64);

            float a0 = hi0 ? a0H : a0L;
            float a1 = hi1 ? a1H : a1L;
            float b0 = hi0 ? b0H : b0L;
            float b1 = hi1 ? b1H : b1L;
            float c0 = hi0 ? c0H : c0L;
            float c1 = hi1 ? c1H : c1L;
            float d0 = hi0 ? d0H : d0L;
            float d1 = hi1 ? d1H : d1L;

            float v00 = a0 * omww + a1 * ww;
            float v01 = b0 * omww + b1 * ww;
            float v10 = c0 * omww + c1 * ww;
            float v11 = d0 * omww + d1 * ww;

            float e0 = v00 + (v01 - v00) * wh;
            float e1 = v10 + (v11 - v10) * wh;
            __builtin_nontemporal_store(e0 + (e1 - e0) * wd, &orow[h * 64]);
        }
    } else {
        #pragma unroll 4
        for (int it = 0; it < 16; ++it) {
            int   h   = wid + it * 4;
            int   rh0 = __builtin_amdgcn_readlane(ho0, h);
            int   rh1 = __builtin_amdgcn_readlane(ho1, h);
            float wh  = __int_as_float(__builtin_amdgcn_readlane(__float_as_int(fr), h));

            float aL = pd0[rh0 + colA];
            float bL = pd0[rh1 + colA];
            float cL = pd1[rh0 + colA];
            float dL = pd1[rh1 + colA];

            float a0 = __shfl(aL, wi0, 64), a1 = __shfl(aL, wi1, 64);
            float b0 = __shfl(bL, wi0, 64), b1 = __shfl(bL, wi1, 64);
            float c0 = __shfl(cL, wi0, 64), c1 = __shfl(cL, wi1, 64);
            float d0 = __shfl(dL, wi0, 64), d1 = __shfl(dL, wi1, 64);

            float v00 = a0 * omww + a1 * ww;
            float v01 = b0 * omww + b1 * ww;
            float v10 = c0 * omww + c1 * ww;
            float v11 = d0 * omww + d1 * ww;

            float e0 = v00 + (v01 - v00) * wh;
            float e1 = v10 + (v11 - v10) * wh;
            __builtin_nontemporal_store(e0 + (e1 - e0) * wd, &orow[h * 64]);
        }
    }
}

extern "C" void kernel_launch(void* const* d_in, const int* in_sizes, int n_in,
                              void* d_out, int out_size, void* d_ws, size_t ws_size,
                              hipStream_t stream) {
    const float* x      = (const float*)d_in[0];
    const int*   sizes  = (const int*)d_in[1];
    const int*   starts = (const int*)d_in[2];
    float*       out    = (float*)d_out;

    int blocks = 256 * 64;   // (crop, d_o)
    crop_resize_kernel<<<blocks, 256, 0, stream>>>(x, sizes, starts, out);
}

// Round 5
// 116.947 us; speedup vs baseline: 1.9080x; 1.3100x over previous
//
#include <hip/hip_runtime.h>

#define IMG 128
#define PLANE (IMG * IMG)
#define VOLSZ (IMG * IMG * IMG)

// One block per (crop, d_o): 256 threads = 4 waves.
// lane = w_out; each wave handles 16 of the 64 h_out rows.
//
// Index-clamp identity: i0' = min(i0, sz-2), fr' = src - i0'. Reference's
// i1 = min(i0+1, sz-1) clamp only fires when i0 = sz-1, which requires
// src = sz-1 exactly (fr = 0); then fr' = 1 and lerp(seg[sz-2], seg[sz-1], 1)
// = seg[sz-1] exactly. So the neighbor is ALWAYS at i0'+1 (in range) and all
// clamp selects vanish.
__global__ __launch_bounds__(256) void crop_resize_kernel(
    const float* __restrict__ x,      // (4,1,128,128,128) f32
    const int* __restrict__ sizes,    // (4,64) i32
    const int* __restrict__ starts,   // (4,64,3) i32
    float* __restrict__ out)          // (256,64,64,64) f32
{
    __shared__ float sbuf[4][512];    // per-wave 4 rows x 128 cols (8 KB)

    // XCD-chunked swizzle (16384 blocks, %8==0 -> bijective)
    int bid  = blockIdx.x;
    int swz  = (bid & 7) * 2048 + (bid >> 3);
    int crop = swz >> 6;
    int d_o  = swz & 63;
    int b    = crop >> 6;

    int sz  = sizes[crop];            // wave-uniform -> scalar
    int s_d = starts[crop * 3 + 0];
    int s_h = starts[crop * 3 + 1];
    int s_w = starts[crop * 3 + 2];

    float szf   = (float)sz;
    float scale = szf * (1.0f / 64.0f);
    float szm1  = szf - 1.0f;
    int   szm2  = sz - 2;

    int lane = threadIdx.x & 63;
    int wid  = __builtin_amdgcn_readfirstlane(threadIdx.x >> 6);

    // per-lane (i0', fr') for j = lane — shared by w and h axes
    float srcj = ((float)lane + 0.5f) * scale - 0.5f;
    srcj = fminf(fmaxf(srcj, 0.0f), szm1);
    int   i0p = min((int)srcj, szm2);
    float frp = srcj - (float)i0p;

    float ww = frp, omww = 1.0f - frp;

    // h axis: per-lane row offset (broadcast via readlane); rh1 = rh0 + IMG
    int ho0 = (s_h + i0p) * IMG;

    // d axis (uniform)
    float srcd = ((float)d_o + 0.5f) * scale - 0.5f;
    srcd = fminf(fmaxf(srcd, 0.0f), szm1);
    int   di0p = min((int)srcd, szm2);
    float wd   = srcd - (float)di0p;

    const float* vol = x + (long long)b * VOLSZ;
    const float* pd0 = vol + (s_d + di0p) * PLANE + s_w;   // pd1 = pd0 + PLANE

    // cooperative segment column offsets (tail-clamped lanes never consumed:
    // s_w + sz <= 128, and reads only touch slots < sz)
    int colA = min(s_w + lane, IMG - 1) - s_w;        // segment[lane]
    int colB = min(s_w + 64 + lane, IMG - 1) - s_w;   // segment[64+lane]

    float* orow = out + (((long long)crop * 64 + d_o) * 64) * 64 + lane;

    if (sz > 64) {
        float* wb = sbuf[wid];
        #pragma unroll 2
        for (int it = 0; it < 16; ++it) {
            int   h   = wid + it * 4;
            int   rh0 = __builtin_amdgcn_readlane(ho0, h);
            float wh  = __int_as_float(__builtin_amdgcn_readlane(__float_as_int(frp), h));

            const float* rA = pd0 + rh0;          // (d0,h0)
            float aL = rA[colA],          aH = rA[colB];
            float bL = rA[IMG + colA],    bH = rA[IMG + colB];
            float cL = rA[PLANE + colA],  cH = rA[PLANE + colB];
            float dL = rA[PLANE + IMG + colA], dH = rA[PLANE + IMG + colB];

            // stage 4 rows (pairs merge to ds_write2_b32)
            wb[lane]       = aL;  wb[64 + lane]  = aH;
            wb[128 + lane] = bL;  wb[192 + lane] = bH;
            wb[256 + lane] = cL;  wb[320 + lane] = cH;
            wb[384 + lane] = dL;  wb[448 + lane] = dH;

            // paired neighbor reads (ds_read2_b32), addresses loop-invariant
            float a0 = wb[i0p],       a1 = wb[i0p + 1];
            float b0 = wb[128 + i0p], b1 = wb[128 + i0p + 1];
            float c0 = wb[256 + i0p], c1 = wb[256 + i0p + 1];
            float d0 = wb[384 + i0p], d1 = wb[384 + i0p + 1];

            float v00 = a0 * omww + a1 * ww;
            float v01 = b0 * omww + b1 * ww;
            float v10 = c0 * omww + c1 * ww;
            float v11 = d0 * omww + d1 * ww;

            float e0 = v00 + (v01 - v00) * wh;
            float e1 = v10 + (v11 - v10) * wh;
            __builtin_nontemporal_store(e0 + (e1 - e0) * wd, &orow[h * 64]);
        }
    } else {
        int pa0 = i0p << 2;           // bpermute byte addresses, precomputed
        int pa1 = pa0 + 4;
        #pragma unroll 4
        for (int it = 0; it < 16; ++it) {
            int   h   = wid + it * 4;
            int   rh0 = __builtin_amdgcn_readlane(ho0, h);
            float wh  = __int_as_float(__builtin_amdgcn_readlane(__float_as_int(frp), h));

            const float* rA = pd0 + rh0;
            float aL = rA[colA];
            float bL = rA[IMG + colA];
            float cL = rA[PLANE + colA];
            float dL = rA[PLANE + IMG + colA];

            float a0 = __int_as_float(__builtin_amdgcn_ds_bpermute(pa0, __float_as_int(aL)));
            float a1 = __int_as_float(__builtin_amdgcn_ds_bpermute(pa1, __float_as_int(aL)));
            float b0 = __int_as_float(__builtin_amdgcn_ds_bpermute(pa0, __float_as_int(bL)));
            float b1 = __int_as_float(__builtin_amdgcn_ds_bpermute(pa1, __float_as_int(bL)));
            float c0 = __int_as_float(__builtin_amdgcn_ds_bpermute(pa0, __float_as_int(cL)));
            float c1 = __int_as_float(__builtin_amdgcn_ds_bpermute(pa1, __float_as_int(cL)));
            float d0 = __int_as_float(__builtin_amdgcn_ds_bpermute(pa0, __float_as_int(dL)));
            float d1 = __int_as_float(__builtin_amdgcn_ds_bpermute(pa1, __float_as_int(dL)));

            float v00 = a0 * omww + a1 * ww;
            float v01 = b0 * omww + b1 * ww;
            float v10 = c0 * omww + c1 * ww;
            float v11 = d0 * omww + d1 * ww;

            float e0 = v00 + (v01 - v00) * wh;
            float e1 = v10 + (v11 - v10) * wh;
            __builtin_nontemporal_store(e0 + (e1 - e0) * wd, &orow[h * 64]);
        }
    }
}

extern "C" void kernel_launch(void* const* d_in, const int* in_sizes, int n_in,
                              void* d_out, int out_size, void* d_ws, size_t ws_size,
                              hipStream_t stream) {
    const float* x      = (const float*)d_in[0];
    const int*   sizes  = (const int*)d_in[1];
    const int*   starts = (const int*)d_in[2];
    float*       out    = (float*)d_out;

    int blocks = 256 * 64;   // (crop, d_o)
    crop_resize_kernel<<<blocks, 256, 0, stream>>>(x, sizes, starts, out);
}

// Round 6
// 113.834 us; speedup vs baseline: 1.9602x; 1.0274x over previous
//
#include <hip/hip_runtime.h>

#define IMG 128
#define PLANE (IMG * IMG)
#define VOLSZ (IMG * IMG * IMG)

// One block per (crop, d_o): 256 threads = 4 waves; lane = w_out; each wave
// handles 16 of the 64 h rows. Per iter the wave needs 4 input rows
// (d0/d1 x h0/h1), all at fixed offsets from one scalar rh0. Cooperative
// load: rowsel = lane>>4 picks the row, (lane&15)*4 the float4 column ->
// ONE global_load_dwordx4 covers 4 rows x 64 cols (2 loads if the segment
// spans >64 slots). Stage to per-wave LDS (ds_write_b128), extract pairs
// with loop-invariant ds_read2_b32.
//
// Index-clamp identity: i0' = min(i0, sz-2), fr' = src - i0'; the reference
// clamp i1 = min(i0+1, sz-1) only fires at fr = 0 where fr' = 1 reproduces
// seg[sz-1] exactly -> neighbor always i0'+1, no selects.
__global__ __launch_bounds__(256) void crop_resize_kernel(
    const float* __restrict__ x,      // (4,1,128,128,128) f32
    const int* __restrict__ sizes,    // (4,64) i32
    const int* __restrict__ starts,   // (4,64,3) i32
    float* __restrict__ out)          // (256,64,64,64) f32
{
    __shared__ float sbuf[4][512];    // per-wave: 4 rows x 128 slots (8 KB)

    // XCD-chunked swizzle (16384 blocks, %8==0 -> bijective)
    int bid  = blockIdx.x;
    int swz  = (bid & 7) * 2048 + (bid >> 3);
    int crop = swz >> 6;
    int d_o  = swz & 63;
    int b    = crop >> 6;

    int sz  = sizes[crop];            // wave-uniform -> scalar
    int s_d = starts[crop * 3 + 0];
    int s_h = starts[crop * 3 + 1];
    int s_w = starts[crop * 3 + 2];

    float szf   = (float)sz;
    float scale = szf * (1.0f / 64.0f);
    float szm1  = szf - 1.0f;
    int   szm2  = sz - 2;

    int lane = threadIdx.x & 63;
    int wid  = __builtin_amdgcn_readfirstlane((int)threadIdx.x >> 6);

    // per-lane (i0', fr') for j = lane — shared by w and h axes
    float srcj = ((float)lane + 0.5f) * scale - 0.5f;
    srcj = fminf(fmaxf(srcj, 0.0f), szm1);
    int   i0p = min((int)srcj, szm2);
    float frp = srcj - (float)i0p;
    float ww = frp, omww = 1.0f - frp;

    // h axis: per-lane row offset (broadcast via readlane); row1 = row0+IMG
    int ho0 = (s_h + i0p) * IMG;

    // d axis (uniform)
    float srcd = ((float)d_o + 0.5f) * scale - 0.5f;
    srcd = fminf(fmaxf(srcd, 0.0f), szm1);
    int   di0p = min((int)srcd, szm2);
    float wd   = srcd - (float)di0p;

    // 16B-aligned anchor for cooperative loads
    int base0 = s_w & ~3;
    int phase = s_w & 3;              // extraction shift; sz-1+phase <= 127

    const float* prow = x + (long long)b * VOLSZ + (s_d + di0p) * PLANE + base0;

    // cooperative loader geometry
    int rsel   = lane >> 4;                       // 0..3: (d,h) row select
    int k4     = (lane & 15) << 2;                // float4 column
    int rowoff = (rsel & 1) * IMG + (rsel >> 1) * PLANE;
    int gA = min(base0 + k4,      IMG - 4) - base0;   // clamped, 16B-aligned
    int gB = min(base0 + 64 + k4, IMG - 4) - base0;   // (clamped lanes write
                                                      //  identical values)
    float* wb    = sbuf[wid];
    float* wrowA = wb + rsel * 128 + gA;
    float* wrowB = wb + rsel * 128 + gB;
    int    eidx  = i0p + phase;       // loop-invariant extraction slot

    float* orow = out + ((long long)crop * 64 + d_o) * 4096 + lane;

    if (sz + phase > 64) {            // need slots up to sz-1+phase > 63
        #pragma unroll 4
        for (int it = 0; it < 16; ++it) {
            int   h   = wid + it * 4;
            int   rh0 = __builtin_amdgcn_readlane(ho0, h);
            float wh  = __int_as_float(__builtin_amdgcn_readlane(__float_as_int(frp), h));

            const float* src = prow + rh0 + rowoff;
            float4 vA = *(const float4*)(src + gA);
            float4 vB = *(const float4*)(src + gB);
            *(float4*)wrowA = vA;
            *(float4*)wrowB = vB;

            float a0 = wb[eidx],        a1 = wb[eidx + 1];
            float b0 = wb[128 + eidx],  b1 = wb[128 + eidx + 1];
            float c0 = wb[256 + eidx],  c1 = wb[256 + eidx + 1];
            float d0 = wb[384 + eidx],  d1 = wb[384 + eidx + 1];

            float v00 = a0 * omww + a1 * ww;
            float v01 = b0 * omww + b1 * ww;
            float v10 = c0 * omww + c1 * ww;
            float v11 = d0 * omww + d1 * ww;
            float e0 = v00 + (v01 - v00) * wh;
            float e1 = v10 + (v11 - v10) * wh;
            __builtin_nontemporal_store(e0 + (e1 - e0) * wd, &orow[h * 64]);
        }
    } else {
        #pragma unroll 4
        for (int it = 0; it < 16; ++it) {
            int   h   = wid + it * 4;
            int   rh0 = __builtin_amdgcn_readlane(ho0, h);
            float wh  = __int_as_float(__builtin_amdgcn_readlane(__float_as_int(frp), h));

            const float* src = prow + rh0 + rowoff;
            float4 vA = *(const float4*)(src + gA);
            *(float4*)wrowA = vA;

            float a0 = wb[eidx],        a1 = wb[eidx + 1];
            float b0 = wb[128 + eidx],  b1 = wb[128 + eidx + 1];
            float c0 = wb[256 + eidx],  c1 = wb[256 + eidx + 1];
            float d0 = wb[384 + eidx],  d1 = wb[384 + eidx + 1];

            float v00 = a0 * omww + a1 * ww;
            float v01 = b0 * omww + b1 * ww;
            float v10 = c0 * omww + c1 * ww;
            float v11 = d0 * omww + d1 * ww;
            float e0 = v00 + (v01 - v00) * wh;
            float e1 = v10 + (v11 - v10) * wh;
            __builtin_nontemporal_store(e0 + (e1 - e0) * wd, &orow[h * 64]);
        }
    }
}

extern "C" void kernel_launch(void* const* d_in, const int* in_sizes, int n_in,
                              void* d_out, int out_size, void* d_ws, size_t ws_size,
                              hipStream_t stream) {
    const float* x      = (const float*)d_in[0];
    const int*   sizes  = (const int*)d_in[1];
    const int*   starts = (const int*)d_in[2];
    float*       out    = (float*)d_out;

    int blocks = 256 * 64;   // (crop, d_o)
    crop_resize_kernel<<<blocks, 256, 0, stream>>>(x, sizes, starts, out);
}